// Round 17
// baseline (89.632 us; speedup 1.0000x reference)
//
#include <hip/hip_runtime.h>
#include <hip/hip_bf16.h>
#include <cstdint>

// Conv2d 3x3 s1 p1, NCHW fp32 -> implicit GEMM on bf16 MFMA.
// x: [32][128][56][56] f32, filters: [256][128][3][3] f32, biases: [256] f32
// out: [32][256][56][56] f32
// ws: Xp (NHWC padded bf16 [32][58][58][128]) then AFrag (bf16, 576KB).
//
// R17 = R14 with B-dedup via 512-thread blocks: one block covers BOTH
// mt-halves of a pixel-tile (8 waves = 2mt x 2wr x 2wc), so B is staged
// ONCE per pt (GB traffic and LDS writes halve). Per-wave structure is
// R14 verbatim: 64x64 tile, A direct-to-VGPR no-copy ping-pong, ring-4
// B bufs (8KB), ONE vmcnt(8) + ONE barrier per 2 K-tiles. 128 regs/wave
// -> 4 waves/SIMD (16 waves/CU). Grid 784 (8x98 XCD-bijective).

typedef __bf16 bf16x8 __attribute__((ext_vector_type(8)));
typedef float f32x4 __attribute__((ext_vector_type(4)));

#define XP_ELEMS (32 * 430592)            // 58*58*128 per image
#define XP_BYTES (XP_ELEMS * 2)           // 27,557,888
#define AF_ELEMS (9 * 256 * 128)          // 294,912 (576KB bf16)

__device__ __forceinline__ unsigned short f2bf(float f) {
  __bf16 b = (__bf16)f;
  return __builtin_bit_cast(unsigned short, b);
}

__device__ __forceinline__ void gload16(const void* g, void* l) {
  __builtin_amdgcn_global_load_lds(
      (const __attribute__((address_space(1))) unsigned int*)g,
      (__attribute__((address_space(3))) unsigned int*)l,
      16, 0, 0);
}

// ---- fused prep: x->Xp (NHWC padded bf16), border zero, filters->AFrag --
__global__ __launch_bounds__(256) void prep_all(const float* __restrict__ x,
                                                const float* __restrict__ f,
                                                unsigned short* __restrict__ xp,
                                                unsigned short* __restrict__ af) {
  int b = blockIdx.x;
  int t = threadIdx.x;
  if (b < 6272) {
    __shared__ unsigned short lt[64][34];
    int hwt = b % 49;
    int ct  = (b / 49) & 3;
    int n   = b / 196;
    int c_loc = t >> 3, col8 = t & 7;
    int hw0 = hwt << 6, c0 = ct << 5;

    const float* src = x + ((n * 128 + c0 + c_loc) * 3136 + hw0 + (col8 << 3));
    float4 v0 = *(const float4*)src;
    float4 v1 = *(const float4*)(src + 4);
    int hb = col8 << 3;
    lt[hb + 0][c_loc] = f2bf(v0.x);
    lt[hb + 1][c_loc] = f2bf(v0.y);
    lt[hb + 2][c_loc] = f2bf(v0.z);
    lt[hb + 3][c_loc] = f2bf(v0.w);
    lt[hb + 4][c_loc] = f2bf(v1.x);
    lt[hb + 5][c_loc] = f2bf(v1.y);
    lt[hb + 6][c_loc] = f2bf(v1.z);
    lt[hb + 7][c_loc] = f2bf(v1.w);
    __syncthreads();

    int hwl = t >> 2, cs = t & 3;
    const unsigned int* lr = (const unsigned int*)&lt[hwl][cs << 3];
    uint4 o = make_uint4(lr[0], lr[1], lr[2], lr[3]);
    int hw = hw0 + hwl;
    int hp = hw / 56 + 1, wp = hw % 56 + 1;
    unsigned short* dst = xp + (n * 430592 + (hp * 58 + wp) * 128 + c0 + (cs << 3));
    *(uint4*)dst = o;
  } else if (b < 6728) {
    int idx = (b - 6272) * 256 + t;
    int img = idx / 3648;
    int j = idx - img * 3648;
    int u4off;
    if (j < 928) {
      u4off = j;
    } else if (j < 1856) {
      u4off = 52896 + (j - 928);
    } else {
      int k = j - 1856;
      int hp = 1 + (k >> 5);
      int r = k & 31;
      int wp = (r < 16) ? 0 : 57;
      u4off = (hp * 58 + wp) * 16 + (r & 15);
    }
    uint4 z = make_uint4(0u, 0u, 0u, 0u);
    *((uint4*)xp + img * 53824 + u4off) = z;
  } else {
    // AFrag[q][g][lane][8]: q = tap*4+ct, g = 16-row group of k-out,
    // lane l=(r15,hi): kout = g*16 + r15, c = ct*32 + hi*8 + e.
    int idx = (b - 6728) * 256 + t;     // < 36864
    int q = idx >> 10;
    int g = (idx >> 6) & 15;
    int l = idx & 63;
    int tap = q >> 2, ct = q & 3;
    int kout = g * 16 + (l & 15);
    int c0 = ct * 32 + ((l >> 4) << 3);
    unsigned short v[8];
#pragma unroll
    for (int e = 0; e < 8; ++e)
      v[e] = f2bf(f[(kout * 128 + c0 + e) * 9 + tap]);
    *(uint4*)(af + idx * 8) = *(const uint4*)v;
  }
}

#define MF(A, B, C) __builtin_amdgcn_mfma_f32_16x16x32_bf16((A), (B), (C), 0, 0, 0)

// ---- main: 256(M)x128(N) block, 8 waves (2mt x 2wr x 2wc), per-wave
// ---- 64x64. A-in-reg no-copy ping-pong, ring-4 shared B LDS (staged
// ---- once per pt), 2 K-tiles per {vmcnt(8) + barrier} period.
__global__ __launch_bounds__(512, 4) void conv_mfma(const unsigned short* __restrict__ xp,
                                                    const unsigned short* __restrict__ af,
                                                    const float* __restrict__ bias,
                                                    float* __restrict__ out) {
  __shared__ unsigned short ldsB[4 * 4096];  // 4 bufs x 8KB (B only)
  char* ldsc = (char*)ldsB;
  int bid = blockIdx.x;
  int pt = (bid & 7) * 98 + (bid >> 3);      // 784 = 8*98 XCD-bijective
  int t = threadIdx.x;
  int wv = t >> 6, l = t & 63;
  int mt = wv >> 2, wr = (wv >> 1) & 1, wc = wv & 1;
  int r15 = l & 15, hi = l >> 4;

  // B staging (512 threads cover all 128 rows): row0 = t>>2, phys slot t&3,
  // pre-swizzled source slot sd = (t&3) ^ f(row0), f(r)=(r>>1)&3.
  int row0 = t >> 2;
  int sd = (t & 3) ^ ((row0 >> 1) & 3);
  const unsigned short* srcB;
  {
    int p = (pt << 7) + row0;
    int ni = p / 3136, hw = p - ni * 3136;
    srcB = xp + (ni * 430592 + ((hw / 56) * 58 + (hw % 56)) * 128 + sd * 8);
  }
  int stW = wv << 10;   // wave covers rows wv*16..+16 = 1KB of each 8KB buf

#define GB(oB, bufb) gload16(srcB + (oB), ldsc + (bufb) + stW)

  const unsigned short* srcA = af + (mt * 8 + wr * 4) * 512 + l * 8;

  int xr = (r15 >> 1) & 3;
  int boff = ((wc << 6) + r15) * 64 + ((hi ^ xr) << 4);

  f32x4 acc[4][4];
#pragma unroll
  for (int m = 0; m < 4; ++m)
#pragma unroll
    for (int n = 0; n < 4; ++n) acc[m][n] = (f32x4){0.f, 0.f, 0.f, 0.f};

  bf16x8 a0[4], a1[4];
#pragma unroll
  for (int m = 0; m < 4; ++m) a0[m] = *(const bf16x8*)(srcA + m * 512);
#pragma unroll
  for (int m = 0; m < 4; ++m) a1[m] = *(const bf16x8*)(srcA + 8192 + m * 512);
  __builtin_amdgcn_sched_barrier(0);
  GB(0, 0);        // tile 0 -> buf 0
  GB(32, 8192);    // tile 1 -> buf 1
  asm volatile("s_waitcnt vmcnt(0)" ::: "memory");
  __builtin_amdgcn_s_barrier();

#pragma unroll 1
  for (int p = 0; p < 18; ++p) {
    int q0 = 2 * p;
    char* cb0 = ldsc + ((q0 & 3) << 13);   // consumed pair
    char* cb1 = cb0 + 8192;
    int qs0 = (p < 17) ? q0 + 2 : 34;      // staged tiles (clamped tail)
    int qs1 = (p < 17) ? q0 + 3 : 35;
    int dst0 = ((q0 + 2) & 3) << 13;       // dest pair: always opposite
    int dst1 = ((q0 + 3) & 3) << 13;
    int tapA = qs0 >> 2, ctA = qs0 & 3;
    int r3A = (tapA * 43) >> 7;
    int oBs0 = ((r3A * 58 + (tapA - r3A * 3)) << 7) + (ctA << 5);
    int tapB = qs1 >> 2, ctB = qs1 & 3;
    int r3B = (tapB * 43) >> 7;
    int oBs1 = ((r3B * 58 + (tapB - r3B * 3)) << 7) + (ctB << 5);

    // ---- half 0: tile q0 ----
    bf16x8 bb[4];
#pragma unroll
    for (int n = 0; n < 4; ++n) bb[n] = *(const bf16x8*)(cb0 + boff + (n << 10));
    GB(oBs0, dst0);
    GB(oBs1, dst1);
    __builtin_amdgcn_sched_barrier(0);     // pin: GBs issue before A-loads
#pragma unroll
    for (int m = 0; m < 4; ++m)
#pragma unroll
      for (int n = 0; n < 4; ++n)
        acc[m][n] = MF(a0[m], bb[n], acc[m][n]);

    // ---- half 1: tile q0+1 (reload a0/a1 in place, no copies) ----
#pragma unroll
    for (int n = 0; n < 4; ++n) bb[n] = *(const bf16x8*)(cb1 + boff + (n << 10));
#pragma unroll
    for (int m = 0; m < 4; ++m) a0[m] = *(const bf16x8*)(srcA + qs0 * 8192 + m * 512);
#pragma unroll
    for (int m = 0; m < 4; ++m)
#pragma unroll
      for (int n = 0; n < 4; ++n)
        acc[m][n] = MF(a1[m], bb[n], acc[m][n]);
#pragma unroll
    for (int m = 0; m < 4; ++m) a1[m] = *(const bf16x8*)(srcA + qs1 * 8192 + m * 512);

    // outstanding: GB x2 (oldest), a0 x4, a1 x4 -> drain GBs only
    asm volatile("s_waitcnt vmcnt(8)" ::: "memory");
    __builtin_amdgcn_s_barrier();
  }
  asm volatile("s_waitcnt vmcnt(0)" ::: "memory");  // drain dummy loads
#undef GB

  // ---- epilogue: D[row=hi*4+reg][col=r15]; row->k, col->pixel
  int kb = mt * 128 + (wr << 6) + (hi << 2);
  int pb = (pt << 7) + (wc << 6) + r15;
#pragma unroll
  for (int m = 0; m < 4; ++m) {
    int kk = kb + (m << 4);
    float4 bv = *(const float4*)(bias + kk);
#pragma unroll
    for (int n = 0; n < 4; ++n) {
      int p = pb + (n << 4);
      int ni = p / 3136;
      int hw = p - ni * 3136;
      int base = (ni * 256 + kk) * 3136 + hw;
      f32x4 v = acc[m][n];
      out[base] = v[0] + bv.x;
      out[base + 3136] = v[1] + bv.y;
      out[base + 6272] = v[2] + bv.z;
      out[base + 9408] = v[3] + bv.w;
    }
  }
}

// ---- fallback: exact fp32 direct conv (only if ws too small) -----------
__global__ void conv_naive(const float* __restrict__ x, const float* __restrict__ flt,
                           const float* __restrict__ bias, float* __restrict__ out) {
  int idx = blockIdx.x * 256 + threadIdx.x;
  if (idx >= 32 * 256 * 3136) return;
  int hw = idx % 3136;
  int k = (idx / 3136) & 255;
  int n = idx / (3136 * 256);
  int h = hw / 56, w = hw % 56;
  float acc = bias[k];
  for (int c = 0; c < 128; ++c) {
    const float* xc = x + (n * 128 + c) * 3136;
    const float* fc = flt + (k * 128 + c) * 9;
#pragma unroll
    for (int r = 0; r < 3; ++r) {
      int hh = h + r - 1;
      if ((unsigned)hh >= 56u) continue;
#pragma unroll
      for (int s = 0; s < 3; ++s) {
        int ww = w + s - 1;
        if ((unsigned)ww >= 56u) continue;
        acc += xc[hh * 56 + ww] * fc[r * 3 + s];
      }
    }
  }
  out[idx] = acc;
}

extern "C" void kernel_launch(void* const* d_in, const int* in_sizes, int n_in,
                              void* d_out, int out_size, void* d_ws, size_t ws_size,
                              hipStream_t stream) {
  const float* x = (const float*)d_in[0];
  const float* flt = (const float*)d_in[1];
  const float* bias = (const float*)d_in[2];
  float* out = (float*)d_out;

  size_t need = (size_t)XP_BYTES + (size_t)AF_ELEMS * 2;
  if (ws_size < need) {
    conv_naive<<<(32 * 256 * 3136 + 255) / 256, 256, 0, stream>>>(x, flt, bias, out);
    return;
  }

  unsigned short* xp = (unsigned short*)d_ws;
  unsigned short* afrag = (unsigned short*)((char*)d_ws + XP_BYTES);

  prep_all<<<6872, 256, 0, stream>>>(x, flt, xp, afrag);
  conv_mfma<<<784, 512, 0, stream>>>(xp, afrag, bias, out);
}

// Round 18
// 86.569 us; speedup vs baseline: 1.0354x; 1.0354x over previous
//
#include <hip/hip_runtime.h>
#include <hip/hip_bf16.h>
#include <cstdint>

// Conv2d 3x3 s1 p1, NCHW fp32 -> implicit GEMM on bf16 MFMA.
// x: [32][128][56][56] f32, filters: [256][128][3][3] f32, biases: [256] f32
// out: [32][256][56][56] f32
// ws: Xp (NHWC padded bf16 [32][58][58][128]) then AFrag (bf16, 576KB).
//
// FINAL (== R14/R16, session best, reproduced twice: conv 75.4-76.4us,
// total 86.8-87.0us, 785 TF = 31% of dense bf16 peak):
// block tile 128(M=k)x128(N=pix), 4 waves 2x2, per-wave 64x64.
// A direct-to-VGPR from fragment-linear AFrag (L2-hot), ping-pong a0/a1
// with NO register copies (reload into the consumed set each period).
// B via ring-4 LDS bufs (8KB each = 32KB), staged 2 tiles ahead; ONE
// counted vmcnt(8) + ONE s_barrier per 2 K-tiles. 3 blocks/CU.
// Ledger: 11 structural variants all regressed vs this local optimum
// (R17 512-thr B-dedup: 77.5; zero-barrier: 105; zero-LDS: 162; ...).

typedef __bf16 bf16x8 __attribute__((ext_vector_type(8)));
typedef float f32x4 __attribute__((ext_vector_type(4)));

#define XP_ELEMS (32 * 430592)            // 58*58*128 per image
#define XP_BYTES (XP_ELEMS * 2)           // 27,557,888
#define AF_ELEMS (9 * 256 * 128)          // 294,912 (576KB bf16)

__device__ __forceinline__ unsigned short f2bf(float f) {
  __bf16 b = (__bf16)f;
  return __builtin_bit_cast(unsigned short, b);
}

__device__ __forceinline__ void gload16(const void* g, void* l) {
  __builtin_amdgcn_global_load_lds(
      (const __attribute__((address_space(1))) unsigned int*)g,
      (__attribute__((address_space(3))) unsigned int*)l,
      16, 0, 0);
}

// ---- fused prep: x->Xp (NHWC padded bf16), border zero, filters->AFrag --
__global__ __launch_bounds__(256) void prep_all(const float* __restrict__ x,
                                                const float* __restrict__ f,
                                                unsigned short* __restrict__ xp,
                                                unsigned short* __restrict__ af) {
  int b = blockIdx.x;
  int t = threadIdx.x;
  if (b < 6272) {
    __shared__ unsigned short lt[64][34];
    int hwt = b % 49;
    int ct  = (b / 49) & 3;
    int n   = b / 196;
    int c_loc = t >> 3, col8 = t & 7;
    int hw0 = hwt << 6, c0 = ct << 5;

    const float* src = x + ((n * 128 + c0 + c_loc) * 3136 + hw0 + (col8 << 3));
    float4 v0 = *(const float4*)src;
    float4 v1 = *(const float4*)(src + 4);
    int hb = col8 << 3;
    lt[hb + 0][c_loc] = f2bf(v0.x);
    lt[hb + 1][c_loc] = f2bf(v0.y);
    lt[hb + 2][c_loc] = f2bf(v0.z);
    lt[hb + 3][c_loc] = f2bf(v0.w);
    lt[hb + 4][c_loc] = f2bf(v1.x);
    lt[hb + 5][c_loc] = f2bf(v1.y);
    lt[hb + 6][c_loc] = f2bf(v1.z);
    lt[hb + 7][c_loc] = f2bf(v1.w);
    __syncthreads();

    int hwl = t >> 2, cs = t & 3;
    const unsigned int* lr = (const unsigned int*)&lt[hwl][cs << 3];
    uint4 o = make_uint4(lr[0], lr[1], lr[2], lr[3]);
    int hw = hw0 + hwl;
    int hp = hw / 56 + 1, wp = hw % 56 + 1;
    unsigned short* dst = xp + (n * 430592 + (hp * 58 + wp) * 128 + c0 + (cs << 3));
    *(uint4*)dst = o;
  } else if (b < 6728) {
    int idx = (b - 6272) * 256 + t;
    int img = idx / 3648;
    int j = idx - img * 3648;
    int u4off;
    if (j < 928) {
      u4off = j;
    } else if (j < 1856) {
      u4off = 52896 + (j - 928);
    } else {
      int k = j - 1856;
      int hp = 1 + (k >> 5);
      int r = k & 31;
      int wp = (r < 16) ? 0 : 57;
      u4off = (hp * 58 + wp) * 16 + (r & 15);
    }
    uint4 z = make_uint4(0u, 0u, 0u, 0u);
    *((uint4*)xp + img * 53824 + u4off) = z;
  } else {
    // AFrag[q][g][lane][8]: q = tap*4+ct, g = 16-row group of k-out,
    // lane l=(r15,hi): kout = g*16 + r15, c = ct*32 + hi*8 + e.
    int idx = (b - 6728) * 256 + t;     // < 36864
    int q = idx >> 10;
    int g = (idx >> 6) & 15;
    int l = idx & 63;
    int tap = q >> 2, ct = q & 3;
    int kout = g * 16 + (l & 15);
    int c0 = ct * 32 + ((l >> 4) << 3);
    unsigned short v[8];
#pragma unroll
    for (int e = 0; e < 8; ++e)
      v[e] = f2bf(f[(kout * 128 + c0 + e) * 9 + tap]);
    *(uint4*)(af + idx * 8) = *(const uint4*)v;
  }
}

#define MF(A, B, C) __builtin_amdgcn_mfma_f32_16x16x32_bf16((A), (B), (C), 0, 0, 0)

// ---- main: 128x128 tile, A-in-reg (no-copy ping-pong), ring-4 B LDS,
// ---- 2 K-tiles per {vmcnt(8) + barrier} period, 3 blocks/CU.
__global__ __launch_bounds__(256, 3) void conv_mfma(const unsigned short* __restrict__ xp,
                                                    const unsigned short* __restrict__ af,
                                                    const float* __restrict__ bias,
                                                    float* __restrict__ out) {
  __shared__ unsigned short ldsB[4 * 4096];  // 4 bufs x 8KB (B only)
  char* ldsc = (char*)ldsB;
  int bid = blockIdx.x;
  int sw = (bid & 7) * 196 + (bid >> 3);     // 1568 = 8*196 XCD-bijective
  int mt = sw & 1;
  int pt = sw >> 1;
  int t = threadIdx.x;
  int wv = t >> 6, l = t & 63;
  int wr = wv >> 1, wc = wv & 1;
  int r15 = l & 15, hi = l >> 4;

  int row0 = t >> 2;
  int sd = (t & 3) ^ ((row0 >> 1) & 3);
  const unsigned short* srcB0;
  const unsigned short* srcB1;
  {
    const unsigned short* sb[2];
#pragma unroll
    for (int j = 0; j < 2; ++j) {
      int p = (pt << 7) + (j << 6) + row0;
      int ni = p / 3136, hw = p - ni * 3136;
      sb[j] = xp + (ni * 430592 + ((hw / 56) * 58 + (hw % 56) ) * 128 + sd * 8);
    }
    srcB0 = sb[0]; srcB1 = sb[1];
  }
  int stW = wv << 10;

#define GB0(oB, bufb) gload16(srcB0 + (oB), ldsc + (bufb) + stW)
#define GB1(oB, bufb) gload16(srcB1 + (oB), ldsc + (bufb) + 4096 + stW)

  const unsigned short* srcA = af + (mt * 8 + wr * 4) * 512 + l * 8;

  int xr = (r15 >> 1) & 3;
  int boff = ((wc << 6) + r15) * 64 + ((hi ^ xr) << 4);

  f32x4 acc[4][4];
#pragma unroll
  for (int m = 0; m < 4; ++m)
#pragma unroll
    for (int n = 0; n < 4; ++n) acc[m][n] = (f32x4){0.f, 0.f, 0.f, 0.f};

  bf16x8 a0[4], a1[4];
#pragma unroll
  for (int m = 0; m < 4; ++m) a0[m] = *(const bf16x8*)(srcA + m * 512);
#pragma unroll
  for (int m = 0; m < 4; ++m) a1[m] = *(const bf16x8*)(srcA + 8192 + m * 512);
  __builtin_amdgcn_sched_barrier(0);
  GB0(0, 0);     GB1(0, 0);        // tile 0 -> buf 0
  GB0(32, 8192); GB1(32, 8192);    // tile 1 -> buf 1
  asm volatile("s_waitcnt vmcnt(0)" ::: "memory");
  __builtin_amdgcn_s_barrier();

#pragma unroll 1
  for (int p = 0; p < 18; ++p) {
    int q0 = 2 * p;
    char* cb0 = ldsc + ((q0 & 3) << 13);   // consumed pair
    char* cb1 = cb0 + 8192;
    int qs0 = (p < 17) ? q0 + 2 : 34;      // staged tiles (clamped tail)
    int qs1 = (p < 17) ? q0 + 3 : 35;
    int dst0 = ((q0 + 2) & 3) << 13;       // dest pair: always opposite
    int dst1 = ((q0 + 3) & 3) << 13;
    int tapA = qs0 >> 2, ctA = qs0 & 3;
    int r3A = (tapA * 43) >> 7;
    int oBs0 = ((r3A * 58 + (tapA - r3A * 3)) << 7) + (ctA << 5);
    int tapB = qs1 >> 2, ctB = qs1 & 3;
    int r3B = (tapB * 43) >> 7;
    int oBs1 = ((r3B * 58 + (tapB - r3B * 3)) << 7) + (ctB << 5);

    // ---- half 0: tile q0 ----
    bf16x8 bb[4];
#pragma unroll
    for (int n = 0; n < 4; ++n) bb[n] = *(const bf16x8*)(cb0 + boff + (n << 10));
    GB0(oBs0, dst0); GB1(oBs0, dst0);
    GB0(oBs1, dst1); GB1(oBs1, dst1);
    __builtin_amdgcn_sched_barrier(0);     // pin: GBs issue before A-loads
#pragma unroll
    for (int m = 0; m < 4; ++m)
#pragma unroll
      for (int n = 0; n < 4; ++n)
        acc[m][n] = MF(a0[m], bb[n], acc[m][n]);

    // ---- half 1: tile q0+1 (reload a0/a1 in place, no copies) ----
#pragma unroll
    for (int n = 0; n < 4; ++n) bb[n] = *(const bf16x8*)(cb1 + boff + (n << 10));
#pragma unroll
    for (int m = 0; m < 4; ++m) a0[m] = *(const bf16x8*)(srcA + qs0 * 8192 + m * 512);
#pragma unroll
    for (int m = 0; m < 4; ++m)
#pragma unroll
      for (int n = 0; n < 4; ++n)
        acc[m][n] = MF(a1[m], bb[n], acc[m][n]);
#pragma unroll
    for (int m = 0; m < 4; ++m) a1[m] = *(const bf16x8*)(srcA + qs1 * 8192 + m * 512);

    // outstanding: GB x4 (oldest), a0 x4, a1 x4 -> drain GBs only
    asm volatile("s_waitcnt vmcnt(8)" ::: "memory");
    __builtin_amdgcn_s_barrier();
  }
  asm volatile("s_waitcnt vmcnt(0)" ::: "memory");  // drain dummy loads
#undef GB0
#undef GB1

  // ---- epilogue: D[row=hi*4+reg][col=r15]; row->k, col->pixel
  int kb = mt * 128 + (wr << 6) + (hi << 2);
  int pb = (pt << 7) + (wc << 6) + r15;
#pragma unroll
  for (int m = 0; m < 4; ++m) {
    int kk = kb + (m << 4);
    float4 bv = *(const float4*)(bias + kk);
#pragma unroll
    for (int n = 0; n < 4; ++n) {
      int p = pb + (n << 4);
      int ni = p / 3136;
      int hw = p - ni * 3136;
      int base = (ni * 256 + kk) * 3136 + hw;
      f32x4 v = acc[m][n];
      out[base] = v[0] + bv.x;
      out[base + 3136] = v[1] + bv.y;
      out[base + 6272] = v[2] + bv.z;
      out[base + 9408] = v[3] + bv.w;
    }
  }
}

// ---- fallback: exact fp32 direct conv (only if ws too small) -----------
__global__ void conv_naive(const float* __restrict__ x, const float* __restrict__ flt,
                           const float* __restrict__ bias, float* __restrict__ out) {
  int idx = blockIdx.x * 256 + threadIdx.x;
  if (idx >= 32 * 256 * 3136) return;
  int hw = idx % 3136;
  int k = (idx / 3136) & 255;
  int n = idx / (3136 * 256);
  int h = hw / 56, w = hw % 56;
  float acc = bias[k];
  for (int c = 0; c < 128; ++c) {
    const float* xc = x + (n * 128 + c) * 3136;
    const float* fc = flt + (k * 128 + c) * 9;
#pragma unroll
    for (int r = 0; r < 3; ++r) {
      int hh = h + r - 1;
      if ((unsigned)hh >= 56u) continue;
#pragma unroll
      for (int s = 0; s < 3; ++s) {
        int ww = w + s - 1;
        if ((unsigned)ww >= 56u) continue;
        acc += xc[hh * 56 + ww] * fc[r * 3 + s];
      }
    }
  }
  out[idx] = acc;
}

extern "C" void kernel_launch(void* const* d_in, const int* in_sizes, int n_in,
                              void* d_out, int out_size, void* d_ws, size_t ws_size,
                              hipStream_t stream) {
  const float* x = (const float*)d_in[0];
  const float* flt = (const float*)d_in[1];
  const float* bias = (const float*)d_in[2];
  float* out = (float*)d_out;

  size_t need = (size_t)XP_BYTES + (size_t)AF_ELEMS * 2;
  if (ws_size < need) {
    conv_naive<<<(32 * 256 * 3136 + 255) / 256, 256, 0, stream>>>(x, flt, bias, out);
    return;
  }

  unsigned short* xp = (unsigned short*)d_ws;
  unsigned short* afrag = (unsigned short*)((char*)d_ws + XP_BYTES);

  prep_all<<<6872, 256, 0, stream>>>(x, flt, xp, afrag);
  conv_mfma<<<1568, 256, 0, stream>>>(xp, afrag, bias, out);
}